// Round 20
// baseline (1015.876 us; speedup 1.0000x reference)
//
#include <hip/hip_runtime.h>

#define CUBE 32

typedef float f32x2 __attribute__((ext_vector_type(2)));
typedef _Float16 half2_t __attribute__((ext_vector_type(2)));

__device__ __forceinline__ float sgpr_f(float v) {
    int i = __builtin_amdgcn_readfirstlane(__float_as_int(v));
    return __int_as_float(i);
}
// 16-lane-row DPP shifts with bound_ctrl=1 (out-of-row lanes read 0).
__device__ __forceinline__ float row_shr1(float v) {   // lane tx <- tx-1; tx=0 -> 0
    return __int_as_float(__builtin_amdgcn_update_dpp(
        0, __float_as_int(v), 0x111, 0xF, 0xF, true));
}
__device__ __forceinline__ float row_shl1(float v) {   // lane tx <- tx+1; tx=15 -> 0
    return __int_as_float(__builtin_amdgcn_update_dpp(
        0, __float_as_int(v), 0x101, 0xF, 0xF, true));
}
// packed 2xf32 fma -> v_pk_fma_f32 (full-rate on CDNA)
__device__ __forceinline__ f32x2 pkfma(f32x2 a, f32x2 b, f32x2 c) {
#if __has_builtin(__builtin_elementwise_fma)
    return __builtin_elementwise_fma(a, b, c);
#else
    f32x2 r; r.x = fmaf(a.x, b.x, c.x); r.y = fmaf(a.y, b.y, c.y); return r;
#endif
}
__device__ __forceinline__ f32x2 h2f_i(int i) {
    union { int v; half2_t h; } u; u.v = i;
    return (f32x2){(float)u.h.x, (float)u.h.y};
}
__device__ __forceinline__ half2_t f2h(f32x2 v) {   // RNE (r9/r15/r18/r19 verified)
    return half2_t{(_Float16)v.x, (_Float16)v.y};
}
#define BLO(v) __builtin_shufflevector(v, v, 0, 0)   // {v.x, v.x} via op_sel
#define BHI(v) __builtin_shufflevector(v, v, 1, 1)   // {v.y, v.y} via op_sel

// ---------------- Kernel A: surface = x @ W_in^T + b_in ----------------
__global__ __launch_bounds__(256) void in_gemm(
    const float* __restrict__ x,
    const float* __restrict__ W_in,
    const float* __restrict__ b_in,
    float* __restrict__ surface)
{
    __shared__ __align__(16) float As[16][68];
    __shared__ __align__(16) float Bs[16][68];
    const int t  = threadIdx.x;
    const int tx = t & 15, ty = t >> 4;
    const int bn = blockIdx.x * 64;
    const int bb = blockIdx.y * 64;

    float acc[4][4];
#pragma unroll
    for (int i = 0; i < 4; ++i)
#pragma unroll
        for (int j = 0; j < 4; ++j) acc[i][j] = 0.0f;

    for (int k0 = 0; k0 < 784; k0 += 16) {
        const int e  = t * 4;
        const int r  = e >> 4;
        const int kk = e & 15;
        float4 av = *(const float4*)&x[(size_t)(bb + r) * 784 + k0 + kk];
        float4 bv = *(const float4*)&W_in[(size_t)(bn + r) * 784 + k0 + kk];
        As[kk + 0][r] = av.x; As[kk + 1][r] = av.y; As[kk + 2][r] = av.z; As[kk + 3][r] = av.w;
        Bs[kk + 0][r] = bv.x; Bs[kk + 1][r] = bv.y; Bs[kk + 2][r] = bv.z; Bs[kk + 3][r] = bv.w;
        __syncthreads();
#pragma unroll
        for (int kki = 0; kki < 16; ++kki) {
            float4 a = *(const float4*)&As[kki][ty * 4];
            float4 b = *(const float4*)&Bs[kki][tx * 4];
            float aa[4] = {a.x, a.y, a.z, a.w};
            float bbv[4] = {b.x, b.y, b.z, b.w};
#pragma unroll
            for (int i = 0; i < 4; ++i)
#pragma unroll
                for (int j = 0; j < 4; ++j)
                    acc[i][j] = fmaf(aa[i], bbv[j], acc[i][j]);
        }
        __syncthreads();
    }
#pragma unroll
    for (int i = 0; i < 4; ++i) {
        const int row = bb + ty * 4 + i;
#pragma unroll
        for (int j = 0; j < 4; ++j) {
            const int col = bn + tx * 4 + j;
            surface[(size_t)row * 1024 + col] = acc[i][j] + b_in[col];
        }
    }
}

// ---------------- Kernel B: cube evolution + output GEMM -----------------
// Co-residency record: r15 (VGPR 64) -> 2 blocks/CU; r18 (76) / r19 (72) ->
// 1 block. Threshold is VGPR<=64 (HW granule likely rounds 72->128), NOT LDS.
// This round: r19's f16/64KB/packed kernel with the pend queue cut from
// depth-8 (16 VGPRs) to the r16-verified depth-4 / 3-slot rotation (6 VGPRs)
// and __launch_bounds__(512,8) to pin VGPR<=64 -> 2 blocks/CU = 4 waves/SIMD.
// r15 proved stalls DO fill at 4 waves/SIMD (it reached its unpacked issue
// wall); packed issue wall is ~2x lower -> expect ~25% on the step loop.

#define REP32(M) M(0)M(1)M(2)M(3)M(4)M(5)M(6)M(7)M(8)M(9)M(10)M(11)M(12)M(13)M(14)M(15)M(16)M(17)M(18)M(19)M(20)M(21)M(22)M(23)M(24)M(25)M(26)M(27)M(28)M(29)M(30)M(31)

// one slot-row accumulation: A += W1*D + W2*{c.x,c.x} + W3*{c.y,c.y}
#define PKROW(A, W1, W2, W3, D, C)                                             \
    A = pkfma(W1, D, A); A = pkfma(W2, BLO(C), A); A = pkfma(W3, BHI(C), A);

// Phase p: barrier every 4; read plane p rows {ym,ty,yp} (half2 as int,
// y-edge rows cndmask'd to 0); cvt; DPP halos -> D pairs; write plane p-4
// from pend PD; accumulate AN/AC/AP; finalize out p-1 into the SAME slot PD.
#define PLANE(p, q, w4, AN, AC, AP, PD) {                                      \
    if ((p) % 4 == 0) __syncthreads();                                         \
    nb_##p = *(const f32x2*)&nbias[(p) * 1024 + nboff];                        \
    int i0 = *(const int*)&S[p][ym][tx2];                                      \
    const int i1 = *(const int*)&S[p][ty][tx2];                                \
    int i2 = *(const int*)&S[p][yp][tx2];                                      \
    if (y0)  i0 = 0;                                                           \
    if (y31) i2 = 0;                                                           \
    const f32x2 c0 = h2f_i(i0);                                                \
    const f32x2 c1 = h2f_i(i1);                                                \
    const f32x2 c2 = h2f_i(i2);                                                \
    const f32x2 D0 = {row_shr1(c0.y), row_shl1(c0.x)};                         \
    const f32x2 D1 = {row_shr1(c1.y), row_shl1(c1.x)};                         \
    const f32x2 D2 = {row_shr1(c2.y), row_shl1(c2.x)};                         \
    if ((p) >= 4) { *(half2_t*)&S[w4][ty][tx2] = f2h(PD); }                    \
    if ((p) < 31) {                                                            \
        PKROW(AN, W1N0, W2N0, W3N0, D0, c0)                                    \
        PKROW(AN, W1N1, W2N1, W3N1, D1, c1)                                    \
        PKROW(AN, W1N2, W2N2, W3N2, D2, c2)                                    \
    }                                                                          \
    PKROW(AC, W1C0, W2C0, W3C0, D0, c0)                                        \
    PKROW(AC, W1C1, W2C1, W3C1, D1, c1)                                        \
    PKROW(AC, W1C2, W2C2, W3C2, D2, c2)                                        \
    if ((p) >= 1) {                                                            \
        PKROW(AP, W1P0, W2P0, W3P0, D0, c0)                                    \
        PKROW(AP, W1P1, W2P1, W3P1, D1, c1)                                    \
        PKROW(AP, W1P2, W2P2, W3P2, D2, c2)                                    \
        f32x2 pre = AP + nb_##q;                                               \
        if ((q) == 0) pre = pre + sf2;                                         \
        const float h0 = 1.0f - 2.0f * __builtin_amdgcn_rcpf(                  \
            __builtin_amdgcn_exp2f(pre.x * 2.8853900817779268f) + 1.0f);       \
        const float h1 = 1.0f - 2.0f * __builtin_amdgcn_rcpf(                  \
            __builtin_amdgcn_exp2f(pre.y * 2.8853900817779268f) + 1.0f);       \
        PD = (f32x2){0.5f, 0.5f} * (cc + (f32x2){h0, h1});                     \
        AP = (f32x2){0.0f, 0.0f};                                              \
    }                                                                          \
    cc = c1;                                                                   \
}

__global__ __launch_bounds__(512, 8) void cube_evolve(
    const float* __restrict__ surface,   // [1024][1024]
    const float* __restrict__ conv_w,    // [27]  (kd,ky,kx)
    const float* __restrict__ nbias,     // [32768] (d,y,x)
    const float* __restrict__ W_out,     // [10][32768]
    const float* __restrict__ b_out,     // [10]
    const int*   __restrict__ steps_p,   // [1]
    float* __restrict__ out)             // [1024][10]
{
    __shared__ __align__(8) _Float16 S[32][32][32];  // 65,536 B

    const int b   = blockIdx.x;
    const int tx  = threadIdx.x;         // 0..15, owns x = 2tx, 2tx+1
    const int ty  = threadIdx.y;         // 0..31
    const int tid = ty * 16 + tx;
    const int tx2 = tx * 2;              // col == x
    const int nboff = ty * 32 + tx2;
    const bool y0 = (ty == 0), y31 = (ty == 31);
    const int ym = y0 ? 0 : ty - 1;      // clamped; value cndmask'd to 0
    const int yp = y31 ? 31 : ty + 1;
    const int steps = steps_p[0];

    // zero state
    for (int i = tid; i < 32 * 32 * 32 / 2; i += 512) ((int*)S)[i] = 0;

    // conv weights -> uniform scalars, then uniform weight PAIRS
    const float cw0  = sgpr_f(conv_w[0]),  cw1  = sgpr_f(conv_w[1]),  cw2  = sgpr_f(conv_w[2]);
    const float cw3  = sgpr_f(conv_w[3]),  cw4  = sgpr_f(conv_w[4]),  cw5  = sgpr_f(conv_w[5]);
    const float cw6  = sgpr_f(conv_w[6]),  cw7  = sgpr_f(conv_w[7]),  cw8  = sgpr_f(conv_w[8]);
    const float cw9  = sgpr_f(conv_w[9]),  cw10 = sgpr_f(conv_w[10]), cw11 = sgpr_f(conv_w[11]);
    const float cw12 = sgpr_f(conv_w[12]), cw13 = sgpr_f(conv_w[13]), cw14 = sgpr_f(conv_w[14]);
    const float cw15 = sgpr_f(conv_w[15]), cw16 = sgpr_f(conv_w[16]), cw17 = sgpr_f(conv_w[17]);
    const float cw18 = sgpr_f(conv_w[18]), cw19 = sgpr_f(conv_w[19]), cw20 = sgpr_f(conv_w[20]);
    const float cw21 = sgpr_f(conv_w[21]), cw22 = sgpr_f(conv_w[22]), cw23 = sgpr_f(conv_w[23]);
    const float cw24 = sgpr_f(conv_w[24]), cw25 = sgpr_f(conv_w[25]), cw26 = sgpr_f(conv_w[26]);

#define MKWP(tag, wl, wc, wr)                                                  \
    const f32x2 W1##tag = {wl, wr};                                            \
    const f32x2 W2##tag = {wc, wl};                                            \
    const f32x2 W3##tag = {wr, wc};
    MKWP(N0, cw0,  cw1,  cw2 )  MKWP(N1, cw3,  cw4,  cw5 )  MKWP(N2, cw6,  cw7,  cw8 )
    MKWP(C0, cw9,  cw10, cw11)  MKWP(C1, cw12, cw13, cw14)  MKWP(C2, cw15, cw16, cw17)
    MKWP(P0, cw18, cw19, cw20)  MKWP(P1, cw21, cw22, cw23)  MKWP(P2, cw24, cw25, cw26)
#undef MKWP

    const f32x2 sf2 = *(const f32x2*)&surface[(size_t)b * 1024 + nboff];

    for (int st = 0; st < steps; ++st) {
#define DECL_NB(d) f32x2 nb_##d;
        REP32(DECL_NB)
#undef DECL_NB
        f32x2 a0 = {0.f, 0.f}, a1 = {0.f, 0.f}, a2 = {0.f, 0.f};
        f32x2 pd0, pd1, pd2;               // pend slots 0,1,2 (depth-4 queue)
        f32x2 cc = {0.f, 0.f};
        // (AN, AC, AP) = slots ((p+1)%3, p%3, (p+2)%3); PD = slot (p+2)%3
        PLANE( 0,  0,  0, a1, a0, a2, pd2)
        PLANE( 1,  0,  0, a2, a1, a0, pd0)
        PLANE( 2,  1,  0, a0, a2, a1, pd1)
        PLANE( 3,  2,  0, a1, a0, a2, pd2)
        PLANE( 4,  3,  0, a2, a1, a0, pd0)
        PLANE( 5,  4,  1, a0, a2, a1, pd1)
        PLANE( 6,  5,  2, a1, a0, a2, pd2)
        PLANE( 7,  6,  3, a2, a1, a0, pd0)
        PLANE( 8,  7,  4, a0, a2, a1, pd1)
        PLANE( 9,  8,  5, a1, a0, a2, pd2)
        PLANE(10,  9,  6, a2, a1, a0, pd0)
        PLANE(11, 10,  7, a0, a2, a1, pd1)
        PLANE(12, 11,  8, a1, a0, a2, pd2)
        PLANE(13, 12,  9, a2, a1, a0, pd0)
        PLANE(14, 13, 10, a0, a2, a1, pd1)
        PLANE(15, 14, 11, a1, a0, a2, pd2)
        PLANE(16, 15, 12, a2, a1, a0, pd0)
        PLANE(17, 16, 13, a0, a2, a1, pd1)
        PLANE(18, 17, 14, a1, a0, a2, pd2)
        PLANE(19, 18, 15, a2, a1, a0, pd0)
        PLANE(20, 19, 16, a0, a2, a1, pd1)
        PLANE(21, 20, 17, a1, a0, a2, pd2)
        PLANE(22, 21, 18, a2, a1, a0, pd0)
        PLANE(23, 22, 19, a0, a2, a1, pd1)
        PLANE(24, 23, 20, a1, a0, a2, pd2)
        PLANE(25, 24, 21, a2, a1, a0, pd0)
        PLANE(26, 25, 22, a0, a2, a1, pd1)
        PLANE(27, 26, 23, a1, a0, a2, pd2)
        PLANE(28, 27, 24, a2, a1, a0, pd0)
        PLANE(29, 28, 25, a0, a2, a1, pd1)
        PLANE(30, 29, 26, a1, a0, a2, pd2)
        PLANE(31, 30, 27, a2, a1, a0, pd0)
        { // tail: finalize output 31 (AC of phase 31 = a1); flush pending
          // planes 28(pd1), 29(pd2), 30(pd0), 31.
            f32x2 pre = a1 + nb_31;
            const float h0 = 1.0f - 2.0f * __builtin_amdgcn_rcpf(
                __builtin_amdgcn_exp2f(pre.x * 2.8853900817779268f) + 1.0f);
            const float h1 = 1.0f - 2.0f * __builtin_amdgcn_rcpf(
                __builtin_amdgcn_exp2f(pre.y * 2.8853900817779268f) + 1.0f);
            const f32x2 v31 = (f32x2){0.5f, 0.5f} * (cc + (f32x2){h0, h1});
            __syncthreads();   // waves may still be reading planes 28..31
            *(half2_t*)&S[28][ty][tx2] = f2h(pd1);
            *(half2_t*)&S[29][ty][tx2] = f2h(pd2);
            *(half2_t*)&S[30][ty][tx2] = f2h(pd0);
            *(half2_t*)&S[31][ty][tx2] = f2h(v31);
        }
    }
    __syncthreads();   // state complete & visible

    // ---- fused output GEMM: out[b][o] = sum_flat s * W_out[o][flat] + b_out[o]
    float p0 = 0.f, p1 = 0.f, p2 = 0.f, p3 = 0.f, p4 = 0.f;
    float p5 = 0.f, p6 = 0.f, p7 = 0.f, p8 = 0.f, p9 = 0.f;
    const int base = tid * 4;
#pragma unroll 4
    for (int j = 0; j < 16; ++j) {
        const int idx = base + j * 2048;
        const int d   = idx >> 10;
        const int rem = idx & 1023;
        const int yy  = rem >> 5;
        const int xx  = rem & 31;          // multiple of 4
        const f32x2 sva = h2f_i(*(const int*)&S[d][yy][xx]);
        const f32x2 svb = h2f_i(*(const int*)&S[d][yy][xx + 2]);
#define OACC(o) { const float4 wv = *(const float4*)&W_out[(size_t)(o) * 32768 + idx]; \
        p##o = fmaf(sva.x, wv.x, p##o); p##o = fmaf(sva.y, wv.y, p##o);        \
        p##o = fmaf(svb.x, wv.z, p##o); p##o = fmaf(svb.y, wv.w, p##o); }
        OACC(0) OACC(1) OACC(2) OACC(3) OACC(4)
        OACC(5) OACC(6) OACC(7) OACC(8) OACC(9)
#undef OACC
    }

    // S is dead now (all GEMM reads done after this barrier) -> reuse as red[]
    __syncthreads();
    float (*red)[8] = (float(*)[8])&S[0][0][0];

    const int lane = tid & 63, wvi = tid >> 6;
#define RED(o) { float t = p##o;                                               \
    t += __shfl_down(t, 32, 64); t += __shfl_down(t, 16, 64);                  \
    t += __shfl_down(t, 8, 64);  t += __shfl_down(t, 4, 64);                   \
    t += __shfl_down(t, 2, 64);  t += __shfl_down(t, 1, 64);                   \
    if (lane == 0) red[o][wvi] = t; }
    RED(0) RED(1) RED(2) RED(3) RED(4) RED(5) RED(6) RED(7) RED(8) RED(9)
#undef RED
    __syncthreads();
    if (tid < 10) {
        float sum = b_out[tid];
#pragma unroll
        for (int w8i = 0; w8i < 8; ++w8i) sum += red[tid][w8i];
        out[(size_t)b * 10 + tid] = sum;
    }
}

// ---------------- launcher ----------------
extern "C" void kernel_launch(void* const* d_in, const int* in_sizes, int n_in,
                              void* d_out, int out_size, void* d_ws, size_t ws_size,
                              hipStream_t stream) {
    const float* x      = (const float*)d_in[0];
    const float* W_in   = (const float*)d_in[1];
    const float* b_in   = (const float*)d_in[2];
    const float* conv_w = (const float*)d_in[3];
    const float* nbias  = (const float*)d_in[4];
    const float* W_out  = (const float*)d_in[5];
    const float* b_out  = (const float*)d_in[6];
    const int*   steps  = (const int*)d_in[7];
    float* out = (float*)d_out;
    float* surface = (float*)d_ws;   // 1024*1024 f32 = 4 MB scratch

    in_gemm<<<dim3(16, 16), 256, 0, stream>>>(x, W_in, b_in, surface);
    cube_evolve<<<1024, dim3(16, 32), 0, stream>>>(surface, conv_w, nbias,
                                                   W_out, b_out, steps, out);
}

// Round 21
// 900.811 us; speedup vs baseline: 1.1277x; 1.1277x over previous
//
#include <hip/hip_runtime.h>

#define CUBE 32

typedef float f32x2 __attribute__((ext_vector_type(2)));

__device__ __forceinline__ float sgpr_f(float v) {
    int i = __builtin_amdgcn_readfirstlane(__float_as_int(v));
    return __int_as_float(i);
}
// 16-lane-row DPP shifts with bound_ctrl=1 (out-of-row lanes read 0).
// DPP rows (16 lanes) == tx dimension: row edges = x=0/x=31 cube boundary ->
// hardware zero-fill = zero halo. (r14/r16/r17: verified passing.)
__device__ __forceinline__ float row_shr1(float v) {   // lane tx <- tx-1; tx=0 -> 0
    return __int_as_float(__builtin_amdgcn_update_dpp(
        0, __float_as_int(v), 0x111, 0xF, 0xF, true));
}
__device__ __forceinline__ float row_shl1(float v) {   // lane tx <- tx+1; tx=15 -> 0
    return __int_as_float(__builtin_amdgcn_update_dpp(
        0, __float_as_int(v), 0x101, 0xF, 0xF, true));
}
// packed 2xf32 fma -> v_pk_fma_f32 (full-rate on CDNA)
__device__ __forceinline__ f32x2 pkfma(f32x2 a, f32x2 b, f32x2 c) {
#if __has_builtin(__builtin_elementwise_fma)
    return __builtin_elementwise_fma(a, b, c);
#else
    f32x2 r; r.x = fmaf(a.x, b.x, c.x); r.y = fmaf(a.y, b.y, c.y); return r;
#endif
}
#define BLO(v) __builtin_shufflevector(v, v, 0, 0)   // {v.x, v.x} via op_sel
#define BHI(v) __builtin_shufflevector(v, v, 1, 1)   // {v.y, v.y} via op_sel

// ---------------- Kernel A: surface = x @ W_in^T + b_in ----------------
__global__ __launch_bounds__(256) void in_gemm(
    const float* __restrict__ x,
    const float* __restrict__ W_in,
    const float* __restrict__ b_in,
    float* __restrict__ surface)
{
    __shared__ __align__(16) float As[16][68];
    __shared__ __align__(16) float Bs[16][68];
    const int t  = threadIdx.x;
    const int tx = t & 15, ty = t >> 4;
    const int bn = blockIdx.x * 64;
    const int bb = blockIdx.y * 64;

    float acc[4][4];
#pragma unroll
    for (int i = 0; i < 4; ++i)
#pragma unroll
        for (int j = 0; j < 4; ++j) acc[i][j] = 0.0f;

    for (int k0 = 0; k0 < 784; k0 += 16) {
        const int e  = t * 4;
        const int r  = e >> 4;
        const int kk = e & 15;
        float4 av = *(const float4*)&x[(size_t)(bb + r) * 784 + k0 + kk];
        float4 bv = *(const float4*)&W_in[(size_t)(bn + r) * 784 + k0 + kk];
        As[kk + 0][r] = av.x; As[kk + 1][r] = av.y; As[kk + 2][r] = av.z; As[kk + 3][r] = av.w;
        Bs[kk + 0][r] = bv.x; Bs[kk + 1][r] = bv.y; Bs[kk + 2][r] = bv.z; Bs[kk + 3][r] = bv.w;
        __syncthreads();
#pragma unroll
        for (int kki = 0; kki < 16; ++kki) {
            float4 a = *(const float4*)&As[kki][ty * 4];
            float4 b = *(const float4*)&Bs[kki][tx * 4];
            float aa[4] = {a.x, a.y, a.z, a.w};
            float bbv[4] = {b.x, b.y, b.z, b.w};
#pragma unroll
            for (int i = 0; i < 4; ++i)
#pragma unroll
                for (int j = 0; j < 4; ++j)
                    acc[i][j] = fmaf(aa[i], bbv[j], acc[i][j]);
        }
        __syncthreads();
    }
#pragma unroll
    for (int i = 0; i < 4; ++i) {
        const int row = bb + ty * 4 + i;
#pragma unroll
        for (int j = 0; j < 4; ++j) {
            const int col = bn + tx * 4 + j;
            surface[(size_t)row * 1024 + col] = acc[i][j] + b_in[col];
        }
    }
}

// ---------------- Kernel B: cube evolution + output GEMM -----------------
// r17 CHAMPION restored (905 us e2e). 512 thr (16tx × 32ty), 2 voxels/thread,
// f32 LDS S[32][34][34], DPP x-halos, packed v_pk_fma_f32 stencil with
// marshalling-free operand pairs, barrier every 8 phases, pend depth 8.
// Post-r20 ledger: occupancy lever structurally closed (live set ~76 VGPR >
// 64-VGPR co-residency granule; r18/r19/r20 all failed to co-reside);
// instruction count near floor (13.5 pk_fma/voxel = 27-tap arithmetic
// minimum); step loop is issue+stall bound at 2 waves/SIMD.

#define REP32(M) M(0)M(1)M(2)M(3)M(4)M(5)M(6)M(7)M(8)M(9)M(10)M(11)M(12)M(13)M(14)M(15)M(16)M(17)M(18)M(19)M(20)M(21)M(22)M(23)M(24)M(25)M(26)M(27)M(28)M(29)M(30)M(31)

// one slot-row accumulation: A += W1*D + W2*{c.x,c.x} + W3*{c.y,c.y}
#define PKROW(A, W1, W2, W3, D, C)                                             \
    A = pkfma(W1, D, A); A = pkfma(W2, BLO(C), A); A = pkfma(W3, BHI(C), A);

// Phase p: barrier every 8; read plane p's 3 own-pair rows (b64); pack DPP
// halos into D pairs; write plane p-8 from pend PDW; accumulate
// AN(out p+1)/AC(out p)/AP(out p-1); finalize out p-1 into pend PDF.
#define PLANE(p, q, w8, AN, AC, AP, PDW, PDF) {                                \
    if ((p) % 8 == 0) __syncthreads();                                         \
    nb_##p = *(const f32x2*)&nbias[(p) * 1024 + nboff];                        \
    const f32x2 c0 = *(const f32x2*)&S[p][ty + 0][tx2];                        \
    const f32x2 c1 = *(const f32x2*)&S[p][ty + 1][tx2];                        \
    const f32x2 c2 = *(const f32x2*)&S[p][ty + 2][tx2];                        \
    const f32x2 D0 = {row_shr1(c0.y), row_shl1(c0.x)};                         \
    const f32x2 D1 = {row_shr1(c1.y), row_shl1(c1.x)};                         \
    const f32x2 D2 = {row_shr1(c2.y), row_shl1(c2.x)};                         \
    if ((p) >= 8) { *(f32x2*)&S[w8][ty + 1][tx2] = PDW; }                      \
    if ((p) < 31) {                                                            \
        PKROW(AN, W1N0, W2N0, W3N0, D0, c0)                                    \
        PKROW(AN, W1N1, W2N1, W3N1, D1, c1)                                    \
        PKROW(AN, W1N2, W2N2, W3N2, D2, c2)                                    \
    }                                                                          \
    PKROW(AC, W1C0, W2C0, W3C0, D0, c0)                                        \
    PKROW(AC, W1C1, W2C1, W3C1, D1, c1)                                        \
    PKROW(AC, W1C2, W2C2, W3C2, D2, c2)                                        \
    if ((p) >= 1) {                                                            \
        PKROW(AP, W1P0, W2P0, W3P0, D0, c0)                                    \
        PKROW(AP, W1P1, W2P1, W3P1, D1, c1)                                    \
        PKROW(AP, W1P2, W2P2, W3P2, D2, c2)                                    \
        f32x2 pre = AP + nb_##q;                                               \
        if ((q) == 0) pre = pre + sf2;                                         \
        const float h0 = 1.0f - 2.0f * __builtin_amdgcn_rcpf(                  \
            __builtin_amdgcn_exp2f(pre.x * 2.8853900817779268f) + 1.0f);       \
        const float h1 = 1.0f - 2.0f * __builtin_amdgcn_rcpf(                  \
            __builtin_amdgcn_exp2f(pre.y * 2.8853900817779268f) + 1.0f);       \
        PDF = (f32x2){0.5f, 0.5f} * (cc + (f32x2){h0, h1});                    \
        AP = (f32x2){0.0f, 0.0f};                                              \
    }                                                                          \
    cc = c1;                                                                   \
}

__global__ __launch_bounds__(512) void cube_evolve(
    const float* __restrict__ surface,   // [1024][1024]
    const float* __restrict__ conv_w,    // [27]  (kd,ky,kx)
    const float* __restrict__ nbias,     // [32768] (d,y,x)
    const float* __restrict__ W_out,     // [10][32768]
    const float* __restrict__ b_out,     // [10]
    const int*   __restrict__ steps_p,   // [1]
    float* __restrict__ out)             // [1024][10]
{
    __shared__ float S[32][34][34];      // rows 0/33 = y-halo (0); cols 32/33 pad
    __shared__ float red[10][8];

    const int b   = blockIdx.x;
    const int tx  = threadIdx.x;         // 0..15, owns x = 2tx, 2tx+1
    const int ty  = threadIdx.y;         // 0..31
    const int tid = ty * 16 + tx;
    const int tx2 = tx * 2;              // col == x (no x-halo offset)
    const int nboff = ty * 32 + tx2;
    const int steps = steps_p[0];

    // zero state + halos + pads
    for (int i = tid; i < 32 * 34 * 34; i += 512) ((float*)S)[i] = 0.0f;

    // conv weights -> uniform scalars, then uniform weight PAIRS
    const float cw0  = sgpr_f(conv_w[0]),  cw1  = sgpr_f(conv_w[1]),  cw2  = sgpr_f(conv_w[2]);
    const float cw3  = sgpr_f(conv_w[3]),  cw4  = sgpr_f(conv_w[4]),  cw5  = sgpr_f(conv_w[5]);
    const float cw6  = sgpr_f(conv_w[6]),  cw7  = sgpr_f(conv_w[7]),  cw8  = sgpr_f(conv_w[8]);
    const float cw9  = sgpr_f(conv_w[9]),  cw10 = sgpr_f(conv_w[10]), cw11 = sgpr_f(conv_w[11]);
    const float cw12 = sgpr_f(conv_w[12]), cw13 = sgpr_f(conv_w[13]), cw14 = sgpr_f(conv_w[14]);
    const float cw15 = sgpr_f(conv_w[15]), cw16 = sgpr_f(conv_w[16]), cw17 = sgpr_f(conv_w[17]);
    const float cw18 = sgpr_f(conv_w[18]), cw19 = sgpr_f(conv_w[19]), cw20 = sgpr_f(conv_w[20]);
    const float cw21 = sgpr_f(conv_w[21]), cw22 = sgpr_f(conv_w[22]), cw23 = sgpr_f(conv_w[23]);
    const float cw24 = sgpr_f(conv_w[24]), cw25 = sgpr_f(conv_w[25]), cw26 = sgpr_f(conv_w[26]);

#define MKWP(tag, wl, wc, wr)                                                  \
    const f32x2 W1##tag = {wl, wr};                                            \
    const f32x2 W2##tag = {wc, wl};                                            \
    const f32x2 W3##tag = {wr, wc};
    MKWP(N0, cw0,  cw1,  cw2 )  MKWP(N1, cw3,  cw4,  cw5 )  MKWP(N2, cw6,  cw7,  cw8 )
    MKWP(C0, cw9,  cw10, cw11)  MKWP(C1, cw12, cw13, cw14)  MKWP(C2, cw15, cw16, cw17)
    MKWP(P0, cw18, cw19, cw20)  MKWP(P1, cw21, cw22, cw23)  MKWP(P2, cw24, cw25, cw26)
#undef MKWP

    const f32x2 sf2 = *(const f32x2*)&surface[(size_t)b * 1024 + nboff];

    for (int st = 0; st < steps; ++st) {
#define DECL_NB(d) f32x2 nb_##d;
        REP32(DECL_NB)
#undef DECL_NB
        f32x2 a0 = {0.f, 0.f}, a1 = {0.f, 0.f}, a2 = {0.f, 0.f};
        f32x2 pd0, pd1, pd2, pd3, pd4, pd5, pd6, pd7;   // pend depth 8
        f32x2 cc = {0.f, 0.f};
        // (AN, AC, AP) = slots ((p+1)%3, p%3, (p+2)%3);
        // PDW = pd[p%8] (write plane p-8); PDF = pd[(p-1)%8] (out p-1).
        PLANE( 0,  0,  0, a1, a0, a2, pd0, pd7)
        PLANE( 1,  0,  0, a2, a1, a0, pd1, pd0)
        PLANE( 2,  1,  0, a0, a2, a1, pd2, pd1)
        PLANE( 3,  2,  0, a1, a0, a2, pd3, pd2)
        PLANE( 4,  3,  0, a2, a1, a0, pd4, pd3)
        PLANE( 5,  4,  0, a0, a2, a1, pd5, pd4)
        PLANE( 6,  5,  0, a1, a0, a2, pd6, pd5)
        PLANE( 7,  6,  0, a2, a1, a0, pd7, pd6)
        PLANE( 8,  7,  0, a0, a2, a1, pd0, pd7)
        PLANE( 9,  8,  1, a1, a0, a2, pd1, pd0)
        PLANE(10,  9,  2, a2, a1, a0, pd2, pd1)
        PLANE(11, 10,  3, a0, a2, a1, pd3, pd2)
        PLANE(12, 11,  4, a1, a0, a2, pd4, pd3)
        PLANE(13, 12,  5, a2, a1, a0, pd5, pd4)
        PLANE(14, 13,  6, a0, a2, a1, pd6, pd5)
        PLANE(15, 14,  7, a1, a0, a2, pd7, pd6)
        PLANE(16, 15,  8, a2, a1, a0, pd0, pd7)
        PLANE(17, 16,  9, a0, a2, a1, pd1, pd0)
        PLANE(18, 17, 10, a1, a0, a2, pd2, pd1)
        PLANE(19, 18, 11, a2, a1, a0, pd3, pd2)
        PLANE(20, 19, 12, a0, a2, a1, pd4, pd3)
        PLANE(21, 20, 13, a1, a0, a2, pd5, pd4)
        PLANE(22, 21, 14, a2, a1, a0, pd6, pd5)
        PLANE(23, 22, 15, a0, a2, a1, pd7, pd6)
        PLANE(24, 23, 16, a1, a0, a2, pd0, pd7)
        PLANE(25, 24, 17, a2, a1, a0, pd1, pd0)
        PLANE(26, 25, 18, a0, a2, a1, pd2, pd1)
        PLANE(27, 26, 19, a1, a0, a2, pd3, pd2)
        PLANE(28, 27, 20, a2, a1, a0, pd4, pd3)
        PLANE(29, 28, 21, a0, a2, a1, pd5, pd4)
        PLANE(30, 29, 22, a1, a0, a2, pd6, pd5)
        PLANE(31, 30, 23, a2, a1, a0, pd7, pd6)
        { // tail: finalize output 31 (AC of phase 31 = a1); pending outputs
          // 24..30 live in pd0..pd6 (finalized at phases 25..31).
            f32x2 pre = a1 + nb_31;
            const float h0 = 1.0f - 2.0f * __builtin_amdgcn_rcpf(
                __builtin_amdgcn_exp2f(pre.x * 2.8853900817779268f) + 1.0f);
            const float h1 = 1.0f - 2.0f * __builtin_amdgcn_rcpf(
                __builtin_amdgcn_exp2f(pre.y * 2.8853900817779268f) + 1.0f);
            const f32x2 v31 = (f32x2){0.5f, 0.5f} * (cc + (f32x2){h0, h1});
            __syncthreads();   // waves may still be reading planes 24..31
            *(f32x2*)&S[24][ty + 1][tx2] = pd0;
            *(f32x2*)&S[25][ty + 1][tx2] = pd1;
            *(f32x2*)&S[26][ty + 1][tx2] = pd2;
            *(f32x2*)&S[27][ty + 1][tx2] = pd3;
            *(f32x2*)&S[28][ty + 1][tx2] = pd4;
            *(f32x2*)&S[29][ty + 1][tx2] = pd5;
            *(f32x2*)&S[30][ty + 1][tx2] = pd6;
            *(f32x2*)&S[31][ty + 1][tx2] = v31;
        }
    }
    __syncthreads();   // state complete & visible

    // ---- fused output GEMM: out[b][o] = sum_flat s * W_out[o][flat] + b_out[o]
    float p0 = 0.f, p1 = 0.f, p2 = 0.f, p3 = 0.f, p4 = 0.f;
    float p5 = 0.f, p6 = 0.f, p7 = 0.f, p8 = 0.f, p9 = 0.f;
    const int base = tid * 4;
#pragma unroll 4
    for (int j = 0; j < 16; ++j) {
        const int idx = base + j * 2048;
        const int d   = idx >> 10;
        const int rem = idx & 1023;
        const int yy  = rem >> 5;
        const int xx  = rem & 31;          // multiple of 4; col == x
        const f32x2 sva = *(const f32x2*)&S[d][yy + 1][xx];
        const f32x2 svb = *(const f32x2*)&S[d][yy + 1][xx + 2];
#define OACC(o) { const float4 wv = *(const float4*)&W_out[(size_t)(o) * 32768 + idx]; \
        p##o = fmaf(sva.x, wv.x, p##o); p##o = fmaf(sva.y, wv.y, p##o);        \
        p##o = fmaf(svb.x, wv.z, p##o); p##o = fmaf(svb.y, wv.w, p##o); }
        OACC(0) OACC(1) OACC(2) OACC(3) OACC(4)
        OACC(5) OACC(6) OACC(7) OACC(8) OACC(9)
#undef OACC
    }

    const int lane = tid & 63, wvi = tid >> 6;
#define RED(o) { float t = p##o;                                               \
    t += __shfl_down(t, 32, 64); t += __shfl_down(t, 16, 64);                  \
    t += __shfl_down(t, 8, 64);  t += __shfl_down(t, 4, 64);                   \
    t += __shfl_down(t, 2, 64);  t += __shfl_down(t, 1, 64);                   \
    if (lane == 0) red[o][wvi] = t; }
    RED(0) RED(1) RED(2) RED(3) RED(4) RED(5) RED(6) RED(7) RED(8) RED(9)
#undef RED
    __syncthreads();
    if (tid < 10) {
        float sum = b_out[tid];
#pragma unroll
        for (int w8i = 0; w8i < 8; ++w8i) sum += red[tid][w8i];
        out[(size_t)b * 10 + tid] = sum;
    }
}

// ---------------- launcher ----------------
extern "C" void kernel_launch(void* const* d_in, const int* in_sizes, int n_in,
                              void* d_out, int out_size, void* d_ws, size_t ws_size,
                              hipStream_t stream) {
    const float* x      = (const float*)d_in[0];
    const float* W_in   = (const float*)d_in[1];
    const float* b_in   = (const float*)d_in[2];
    const float* conv_w = (const float*)d_in[3];
    const float* nbias  = (const float*)d_in[4];
    const float* W_out  = (const float*)d_in[5];
    const float* b_out  = (const float*)d_in[6];
    const int*   steps  = (const int*)d_in[7];
    float* out = (float*)d_out;
    float* surface = (float*)d_ws;   // 1024*1024 f32 = 4 MB scratch

    in_gemm<<<dim3(16, 16), 256, 0, stream>>>(x, W_in, b_in, surface);
    cube_evolve<<<1024, dim3(16, 32), 0, stream>>>(surface, conv_w, nbias,
                                                   W_out, b_out, steps, out);
}